// Round 5
// baseline (256.903 us; speedup 1.0000x reference)
//
#include <hip/hip_runtime.h>

#define GROUPSIZE 128
#define IN_F 4096
#define OUT_F 11008
#define TOKENS 512
#define N_GROUPS (OUT_F * IN_F / GROUPSIZE)  // 352256
#define NGK (IN_F / GROUPSIZE)               // 32 groups per row

#define BM 64
#define BN 128
#define BK 64
#define NTHREADS 256
#define NT_G (IN_F / BK)     // 64 global K-steps
#define NT_H (NT_G / 2)      // 32 per k-half (split-K x2)
#define NTILES_N (OUT_F / BN) // 86

typedef _Float16 half8  __attribute__((ext_vector_type(8)));
typedef _Float16 half2v __attribute__((ext_vector_type(2)));
typedef float    f32x4  __attribute__((ext_vector_type(4)));
typedef int      ivec4  __attribute__((ext_vector_type(4)));

// A-tile halfword swizzle ([64 rows][64 hw], 128B rows): XOR 16B-granule by
// row&7 -> conflict-free ds_read_b128 frags (verified R1-R4).
__device__ __forceinline__ int swz(int r, int k) {
    return ((r << 6) + k) ^ ((r & 7) << 3);
}

__device__ __forceinline__ void glds16(const _Float16* g, _Float16* l) {
    __builtin_amdgcn_global_load_lds(
        (const __attribute__((address_space(1))) void*)g,
        (__attribute__((address_space(3))) void*)l, 16, 0, 0);
}

// pack 4 int32 "bytes" -> 1 dword (8 weights, 4-bit density): 3 v_perm
__device__ __forceinline__ unsigned pack4(ivec4 q) {
    unsigned p01 = __builtin_amdgcn_perm((unsigned)q[1], (unsigned)q[0], 0x0C0C0400u);
    unsigned p23 = __builtin_amdgcn_perm((unsigned)q[3], (unsigned)q[2], 0x0C0C0400u);
    return __builtin_amdgcn_perm(p23, p01, 0x05040100u);   // [b0,b1,b2,b3]
}

// dequant packed dword (8 weights) -> half8 via perm + pk_fma.
// byte e: hi nibble at bits4-7 (fp16 mantissa pos for 64+n), lo nibble <<4.
__device__ __forceinline__ half8 dqp(unsigned p, uint2 sz) {
    unsigned A4 = (p << 4) & 0xF0F0F0F0u;   // lo nibbles -> bits 4-7
    unsigned Bn =  p       & 0xF0F0F0F0u;   // hi nibbles already at 4-7
    unsigned t01 = __builtin_amdgcn_perm(A4, Bn, 0x05010400u); // [hi0,lo0,hi1,lo1]
    unsigned t23 = __builtin_amdgcn_perm(A4, Bn, 0x07030602u); // [hi2,lo2,hi3,lo3]
    const unsigned k54 = 0x54545454u;
    unsigned u0 = __builtin_amdgcn_perm(t01, k54, 0x00050004u); // (64+hi0, 64+lo0)
    unsigned u1 = __builtin_amdgcn_perm(t01, k54, 0x00070006u);
    unsigned u2 = __builtin_amdgcn_perm(t23, k54, 0x00050004u);
    unsigned u3 = __builtin_amdgcn_perm(t23, k54, 0x00070006u);
    half2v S  = __builtin_bit_cast(half2v, sz.x);
    half2v Bv = __builtin_bit_cast(half2v, sz.y);
    union { half8 h; half2v p2[4]; } r;
    r.p2[0] = __builtin_bit_cast(half2v, u0) * S + Bv;
    r.p2[1] = __builtin_bit_cast(half2v, u1) * S + Bv;
    r.p2[2] = __builtin_bit_cast(half2v, u2) * S + Bv;
    r.p2[3] = __builtin_bit_cast(half2v, u3) * S + Bv;
    return r.h;
}

// ---------- pre-kernel 1: x fp32 -> fp16 ----------
__global__ __launch_bounds__(256)
void cvt_x_kernel(const float* __restrict__ x, _Float16* __restrict__ x16) {
    size_t i = ((size_t)blockIdx.x * 256 + threadIdx.x) * 8;
    f32x4 a = *(const f32x4*)(x + i);
    f32x4 b = *(const f32x4*)(x + i + 4);
    half8 h;
    h[0]=(_Float16)a[0]; h[1]=(_Float16)a[1]; h[2]=(_Float16)a[2]; h[3]=(_Float16)a[3];
    h[4]=(_Float16)b[0]; h[5]=(_Float16)b[1]; h[6]=(_Float16)b[2]; h[7]=(_Float16)b[3];
    *(half8*)(x16 + i) = h;
}

// ---------- pre-kernel 2: pack (S, -(64+z)*S) fp16 pairs, TRANSPOSED [gk][row] ----------
__global__ __launch_bounds__(256)
void szpack_kernel(const float* __restrict__ s, const float* __restrict__ z,
                   uint2* __restrict__ szt) {
    int g = blockIdx.x * 256 + threadIdx.x;
    if (g >= N_GROUPS) return;
    int row = g / NGK, gk = g % NGK;
    _Float16 S = (_Float16)s[g];
    _Float16 B = (_Float16)(-(64.0f + z[g]) * (float)S);
    unsigned short su = __builtin_bit_cast(unsigned short, S);
    unsigned short bu = __builtin_bit_cast(unsigned short, B);
    uint2 r;
    r.x = ((unsigned)su << 16) | su;
    r.y = ((unsigned)bu << 16) | bu;
    szt[(size_t)gk * OUT_F + row] = r;
}

// ---------- pre-kernel 3: out = bias (split-K blocks atomicAdd into it) ----------
__global__ __launch_bounds__(256)
void out_init_kernel(const float* __restrict__ bias, float* __restrict__ out) {
    size_t i = ((size_t)blockIdx.x * 256 + threadIdx.x) * 4;
    int col = (int)(i % OUT_F);
    *(f32x4*)(out + i) = *(const f32x4*)(bias + col);
}

__global__ __launch_bounds__(NTHREADS, 4)
void qlinear_main(const _Float16* __restrict__ x16,
                  const int*   __restrict__ qw,
                  const uint2* __restrict__ szt,
                  float*       __restrict__ out)
{
    __shared__ __align__(16) _Float16 As[2][BM * BK];     // 2 x 8 KB
    __shared__ __align__(16) unsigned Qs[2][BN * BK / 8]; // 2 x 4 KB packed q

    // XCD-local: bid&7 = XCD; each XCD owns 11 n-tiles x (8 m x 2 kh).
    const int bid = blockIdx.x;
    const int xcd = bid & 7;
    const int sgrp = bid >> 3;                // 0..175
    const int n_t = 11 * xcd + (sgrp >> 4);
    const int sub = sgrp & 15;
    const int m_t = sub & 7;
    const int kh  = sub >> 3;
    if (n_t >= NTILES_N) return;              // 32 pad blocks idle
    const int n0 = n_t * BN, m0 = m_t * BM;
    const int t0 = kh * NT_H;

    const int tid = threadIdx.x;
    const int wv = tid >> 6, ln = tid & 63;

    // ---- q stager role: thread owns 16B segment s8 of rows r0+32j ----
    const int s8 = tid & 7, r0 = tid >> 3;
    const int* qg = qw + (size_t)(n0 + r0) * (IN_F / 2) + (size_t)t0 * 32 + s8 * 4;
    const int dwp = s8 ^ ((r0 >> 2) & 3);     // swizzled dword slot (const per thread)

    // ---- A stager (glds, inverse-swizzled source) ----
    const int ar  = wv * 16 + (ln >> 3);
    const int gsw = (ln & 7) ^ ((ln >> 3) & 7);
    const _Float16* ag = x16 + (size_t)(m0 + ar) * IN_F + (size_t)t0 * BK + gsw * 8;

    // ---- MFMA role: wave owns 64 x 32 (wc2 = wv*32); dequants its own B rows ----
    const int wc2 = wv * 32;
    const int lr = ln & 15, ln4 = ln >> 4, lk8 = ln4 * 8, lk4 = ln4 * 4;
    int qrd[2][2];
#pragma unroll
    for (int j = 0; j < 2; ++j) {
        int row = wc2 + j * 16 + lr;
        int qx = (row >> 2) & 3;
#pragma unroll
        for (int kk = 0; kk < 2; ++kk)
            qrd[j][kk] = row * 8 + ((kk * 4 + ln4) ^ qx);
    }
    const int szrow = n0 + wc2 + lr;

    f32x4 acc[4][2];
#pragma unroll
    for (int i = 0; i < 4; ++i)
#pragma unroll
        for (int j = 0; j < 2; ++j)
            acc[i][j] = (f32x4){0.f, 0.f, 0.f, 0.f};

#define LOAD_Q(qs, tt) do {                                                 \
        _Pragma("unroll")                                                   \
        for (int j = 0; j < 4; ++j)                                         \
            qs[j] = *(const ivec4*)(qg + (size_t)j * 32 * (IN_F/2) + (tt) * 32); \
    } while (0)

#define STAGE_A(tt, buf) do {                                               \
        const _Float16* gp = ag + (size_t)(tt) * 64;                        \
        glds16(gp,            &As[buf][wv * 1024]);                         \
        glds16(gp + 8 * IN_F, &As[buf][wv * 1024 + 512]);                   \
    } while (0)

#define PACK_STORE(qs, buf) do {                                            \
        _Pragma("unroll")                                                   \
        for (int j = 0; j < 4; ++j)                                         \
            Qs[buf][(r0 + 32 * j) * 8 + dwp] = pack4(qs[j]);                \
    } while (0)

    uint2 szc0, szc1;

    auto mfma_phase = [&](int b) {
#pragma unroll
        for (int kk = 0; kk < 2; ++kk) {
            half8 af[4];
#pragma unroll
            for (int i = 0; i < 4; ++i)
                af[i] = *(const half8*)&As[b][swz(i * 16 + lr, kk * 32 + lk8)];
            {
                half8 bf = dqp(Qs[b][qrd[0][kk]], szc0);
#pragma unroll
                for (int i = 0; i < 4; ++i)
                    acc[i][0] = __builtin_amdgcn_mfma_f32_16x16x32_f16(af[i], bf, acc[i][0], 0, 0, 0);
            }
            {
                half8 bf = dqp(Qs[b][qrd[1][kk]], szc1);
#pragma unroll
                for (int i = 0; i < 4; ++i)
                    acc[i][1] = __builtin_amdgcn_mfma_f32_16x16x32_f16(af[i], bf, acc[i][1], 0, 0, 0);
            }
        }
    };

    // ---- prologue: tile 0 staged; sz(0) loaded ----
    ivec4 qr[4];
    {
        int gk0 = t0 >> 1;
        szc0 = szt[(size_t)gk0 * OUT_F + szrow];
        szc1 = szt[(size_t)gk0 * OUT_F + szrow + 16];
        STAGE_A(0, 0);
        LOAD_Q(qr, 0);
        PACK_STORE(qr, 0);           // waits q regs -> drains glds too
        asm volatile("s_waitcnt vmcnt(0) lgkmcnt(0)" ::: "memory");
        __builtin_amdgcn_s_barrier();
    }

    // ---- main loop: per body, next-tile loads overlap this tile's MFMA ----
    for (int t = 0; t < NT_H; ++t) {
        const int b = t & 1;
        const int tn = (t + 1 < NT_H) ? t + 1 : NT_H - 1;
        const int gkn = (t0 + tn) >> 1;
        uint2 szn0 = szt[(size_t)gkn * OUT_F + szrow];        // sz for tile t+1
        uint2 szn1 = szt[(size_t)gkn * OUT_F + szrow + 16];
        STAGE_A(tn, b ^ 1);                                   // A(t+1) -> LDS
        LOAD_Q(qr, tn);                                       // q(t+1) -> regs
        mfma_phase(b);                                        // compute tile t
        PACK_STORE(qr, b ^ 1);                                // waits q; drains glds
        asm volatile("s_waitcnt lgkmcnt(0)" ::: "memory");
        __builtin_amdgcn_s_barrier();
        szc0 = szn0; szc1 = szn1;
    }

    // ---- epilogue: atomic accumulate (out pre-initialized to bias) ----
#pragma unroll
    for (int j = 0; j < 2; ++j) {
        const int col = n0 + wc2 + j * 16 + lr;
#pragma unroll
        for (int i = 0; i < 4; ++i) {
            const int rb = m0 + i * 16 + lk4;
#pragma unroll
            for (int r = 0; r < 4; ++r)
                atomicAdd(&out[(size_t)(rb + r) * OUT_F + col], acc[i][j][r]);
        }
    }
#undef LOAD_Q
#undef STAGE_A
#undef PACK_STORE
}

extern "C" void kernel_launch(void* const* d_in, const int* in_sizes, int n_in,
                              void* d_out, int out_size, void* d_ws, size_t ws_size,
                              hipStream_t stream) {
    const float* x      = (const float*)d_in[0];
    const int*   qw     = (const int*)d_in[1];
    const float* scales = (const float*)d_in[2];
    const float* zeros  = (const float*)d_in[3];
    const float* bias   = (const float*)d_in[4];
    float*       out    = (float*)d_out;

    _Float16* x16 = (_Float16*)d_ws;                                   // 4 MB
    uint2*    szt = (uint2*)((char*)d_ws + (size_t)TOKENS * IN_F * 2); // 2.75 MB

    cvt_x_kernel<<<TOKENS * IN_F / (256 * 8), 256, 0, stream>>>(x, x16);
    szpack_kernel<<<(N_GROUPS + 255) / 256, 256, 0, stream>>>(scales, zeros, szt);
    out_init_kernel<<<TOKENS * OUT_F / (256 * 4), 256, 0, stream>>>(bias, out);

    // 86 n-tiles x 8 m x 2 kh, XCD-grouped, padded to 1408
    qlinear_main<<<1408, NTHREADS, 0, stream>>>(x16, qw, szt, out);
}